// Round 13
// baseline (57.266 us; speedup 1.0000x reference)
//
#include <hip/hip_runtime.h>
#include <hip/hip_bf16.h>
#include <stdint.h>

typedef __bf16 bf16_t;
typedef __bf16 bf16x8 __attribute__((ext_vector_type(8)));
typedef float  f32x4  __attribute__((ext_vector_type(4)));
typedef float  f32x16 __attribute__((ext_vector_type(16)));
typedef unsigned int uint;
typedef uint uintx4 __attribute__((ext_vector_type(4)));

#define MFMA16(a,b,c) __builtin_amdgcn_mfma_f32_16x16x32_bf16((a),(b),(c),0,0,0)
#define MFMA32(a,b,c) __builtin_amdgcn_mfma_f32_32x32x16_bf16((a),(b),(c),0,0,0)

constexpr int NB = 16;
constexpr int LQ = 8192;
constexpr int LK = 128;
constexpr int H  = 128;

// log2(e) / sqrt(H): fold softmax scale + exp2 conversion into one multiply
constexpr float C1 = 1.4426950408889634f / 11.313708498984761f;

constexpr size_t WS_FLAG = 0;
// per batch 64KB: [M frag-chunks 32KB | V frag-chunks 32KB]  (r11 layout)
constexpr size_t WS_MV   = 1024;

// XOR swizzle for [*][128] bf16 LDS tiles (row stride 256 B) — prep only
__device__ __forceinline__ unsigned swz(unsigned row, unsigned byte) {
  return row * 256u + (byte ^ ((row & 15u) << 4));
}

__device__ __forceinline__ bf16x8 cvt_frag(const float* p) {
  f32x4 u0 = *(const f32x4*)p;
  f32x4 u1 = *(const f32x4*)(p + 4);
  bf16x8 v;
  #pragma unroll
  for (int e = 0; e < 4; ++e) { v[e] = (bf16_t)u0[e]; v[e + 4] = (bf16_t)u1[e]; }
  return v;
}

__device__ __forceinline__ f32x16 zero16() {
  f32x16 z;
  #pragma unroll
  for (int i = 0; i < 16; ++i) z[i] = 0.f;
  return z;
}

// v_cvt_pk_bf16_f32: lo = bf16(a), hi = bf16(b)
__device__ __forceinline__ uint pkbf(float a, float b) {
  uint d;
  asm("v_cvt_pk_bf16_f32 %0, %1, %2" : "=v"(d) : "v"(a), "v"(b));
  return d;
}

// async global->LDS, 16 bytes per lane (LDS dest: wave-uniform base + lane*16;
// global SOURCE is per-lane -> carries the swizzle)
__device__ __forceinline__ void gl16(const void* g, void* l) {
  __builtin_amdgcn_global_load_lds(
      (const __attribute__((address_space(1))) uint32_t*)g,
      (__attribute__((address_space(3))) uint32_t*)l, 16, 0, 0);
}

// ---------------------------------------------------------------------------
// prep (32 blocks): block 2b   -> M_b = x2_b @ (wq^T wk)  (frag-order to ws)
//                   block 2b+1 -> V_b = x2_b @ wv^T       (frag-order to ws)
// (unchanged from r11/r12, validated)
// ---------------------------------------------------------------------------
__global__ __launch_bounds__(512) void prep_kernel(
    const float* __restrict__ x2, const float* __restrict__ wq,
    const float* __restrict__ wk, const float* __restrict__ wv,
    const unsigned* __restrict__ x3w, uint8_t* __restrict__ ws)
{
  __shared__ uint8_t sP[131072];  // [wqT 32K | wkT 32K | W2T lin 32K | out 32K]
  __shared__ int sF32, sBig;
  const int tid = threadIdx.x;
  const int b = blockIdx.x >> 1, which = blockIdx.x & 1;
  const int l = tid & 63, w = tid >> 6, q31 = l & 31, hi2 = l >> 5;
  uint8_t* sOut = sP + 98304;

  if (which == 0) {
    if (blockIdx.x == 0) {
      // mask dtype probe over first 2048 words of x3:
      // int32 bool -> words in {0,1}; uint8 bool -> words like 0x01010101 (>1);
      // f32 bool -> words in {0, 0x3f800000}
      if (tid == 0) { sF32 = 0; sBig = 0; }
      __syncthreads();
      int f = 0, g = 0;
      #pragma unroll
      for (int j = 0; j < 4; ++j) {
        unsigned v = x3w[tid * 4 + j];
        if (v == 0x3f800000u) f = 1;
        else if (v > 1u) g = 1;
      }
      if (f) sF32 = 1;
      if (g) sBig = 1;
      __syncthreads();
      if (tid == 0) *(int*)(ws + WS_FLAG) = (sF32 == 0 && sBig == 1) ? 1 : 0;
    }

    // stage wqT / wkT swizzled
    {
      const int row = tid >> 2, c0 = (tid & 3) * 32;
      #pragma unroll
      for (int wh = 0; wh < 2; ++wh) {
        const float* W = wh ? wk : wq;
        uint8_t* dst = sP + wh * 32768;
        const float* s = W + row * H + c0;
        #pragma unroll
        for (int j = 0; j < 32; ++j)
          *(bf16_t*)(dst + swz(c0 + j, row * 2)) = (bf16_t)s[j];
      }
    }
    __syncthreads();

    // W2T[i][j] = sum_k wq[k][i] wk[k][j]  -> LDS linear [128][128] bf16
    {
      const int lo = l & 15, hi = l >> 4;
      bf16x8 a4[4];
      #pragma unroll
      for (int kk = 0; kk < 4; ++kk)
        a4[kk] = *(const bf16x8*)(sP + swz(16 * w + lo, kk * 64 + hi * 16));
      bf16_t* W2T = (bf16_t*)(sP + 65536);
      #pragma unroll
      for (int t = 0; t < 8; ++t) {
        f32x4 c = {0.f, 0.f, 0.f, 0.f};
        #pragma unroll
        for (int kk = 0; kk < 4; ++kk)
          c = MFMA16(a4[kk], *(const bf16x8*)(sP + 32768 + swz(16 * t + lo, kk * 64 + hi * 16)), c);
        #pragma unroll
        for (int r = 0; r < 4; ++r)
          W2T[(16 * w + hi * 4 + r) * H + 16 * t + lo] = (bf16_t)c[r];
      }
    }
    __syncthreads();

    // M build
    if (w < 4) {
      const int wb = w;
      bf16x8 axf[8];
      const float* x2r = x2 + ((size_t)b * LK + 32 * wb + q31) * H;
      #pragma unroll
      for (int kt = 0; kt < 8; ++kt)
        axf[kt] = cvt_frag(x2r + kt * 16 + 8 * hi2);
      const bf16_t* W2Tl = (const bf16_t*)(sP + 65536);
      #pragma unroll
      for (int nt = 0; nt < 4; ++nt) {
        f32x16 c = zero16();
        #pragma unroll
        for (int kt = 0; kt < 8; ++kt)
          c = MFMA32(axf[kt],
                     *(const bf16x8*)(W2Tl + (size_t)(nt * 32 + q31) * H + kt * 16 + 8 * hi2), c);
        #pragma unroll
        for (int r = 0; r < 16; ++r)
          *(bf16_t*)(sOut + swz(32 * wb + (r & 3) + 8 * (r >> 2) + 4 * hi2,
                                (nt * 32 + q31) * 2)) = (bf16_t)c[r];
      }
    }
  } else {
    // V build
    if (w < 4) {
      const int wb = w;
      bf16x8 axf[8];
      const float* x2r = x2 + ((size_t)b * LK + 32 * wb + q31) * H;
      #pragma unroll
      for (int kt = 0; kt < 8; ++kt)
        axf[kt] = cvt_frag(x2r + kt * 16 + 8 * hi2);
      #pragma unroll
      for (int nt = 0; nt < 4; ++nt) {
        f32x16 c = zero16();
        #pragma unroll
        for (int kt = 0; kt < 8; ++kt)
          c = MFMA32(axf[kt],
                     cvt_frag(wv + (size_t)(nt * 32 + q31) * H + kt * 16 + 8 * hi2), c);
        #pragma unroll
        for (int r = 0; r < 16; ++r)
          *(bf16_t*)(sOut + swz(32 * wb + (r & 3) + 8 * (r >> 2) + 4 * hi2,
                                (nt * 32 + q31) * 2)) = (bf16_t)c[r];
      }
    }
  }
  __syncthreads();

  // repack swizzled image -> fragment-major chunks in ws.
  {
    uint8_t* dst = ws + WS_MV + (size_t)b * 65536 + (size_t)which * 32768;
    #pragma unroll
    for (int pass = 0; pass < 4; ++pass) {
      const int idx = tid + pass * 512;         // 0..2047
      const int chunk = idx >> 6, le = idx & 63;
      const int t4 = chunk >> 3, kt = chunk & 7;
      bf16x8 v = *(const bf16x8*)(sOut + swz(t4 * 32 + (le & 31),
                                             kt * 32 + (le >> 5) * 16));
      *(bf16x8*)(dst + (size_t)idx * 16) = v;
    }
  }
}

// ---------------------------------------------------------------------------
// Main fused kernel — r12 math + global_load_lds staging (zero-VGPR
// concurrency) with PRE-SWIZZLED SOURCE addresses (LDS dest linear, the
// global per-lane source carries the XOR so LDS reads are conflict-light).
// Each wave stages its OWN 32 rows of x1 (f32) + mask -> LDS is wave-private
// -> NO barriers; a single s_waitcnt vmcnt(0) separates stage from compute.
// Per wave 20 KB of fire-and-forget loads in flight (vs ~4 KB reg-staged).
// LDS 80 KB -> 2 blocks/CU = 8 waves/CU.
// ---------------------------------------------------------------------------
__global__ __launch_bounds__(256, 2) void attn_kernel(
    const float* __restrict__ x1, const void* __restrict__ x3,
    const uint8_t* __restrict__ ws, float* __restrict__ out)
{
  __shared__ uint8_t sX[65536];   // x1 tile f32 [128 rows][512 B], src-swizzled
  __shared__ uint8_t sMk[16384];  // mask tile [128 rows][128 B], src-swizzled

  const int tid = threadIdx.x, blk = blockIdx.x;
  const int b = blk >> 6, qc = (blk & 63) * 128;
  const int l = tid & 63, w4 = tid >> 6;
  const int q31 = l & 31, hi2 = l >> 5;
  const int byteMode = *(const int*)(ws + WS_FLAG);

  const int q0w = qc + w4 * 32;
  const size_t qrow = (size_t)b * LQ + q0w + q31;   // this lane's q row

  const uint8_t* Mf = ws + WS_MV + (size_t)b * 65536;
  const uint8_t* Vf = Mf + 32768;

  // ---- stage x1 rows (own wave's 32) via gl16, source pre-swizzled ----
  {
    const uint8_t* xgb = (const uint8_t*)(x1 + ((size_t)b * LQ + qc) * H);
    #pragma unroll
    for (int j = 0; j < 16; ++j) {
      const int off = w4 * 16384 + j * 1024 + l * 16;
      const int row = off >> 9;              // 512 B per f32 row
      const int wb  = off & 511;
      gl16(xgb + row * 512 + (wb ^ ((row & 31) << 4)), sX + off);
    }
    if (byteMode) {
      const uint8_t* mgb = (const uint8_t*)x3 + ((size_t)b * LQ + qc) * LK;
      #pragma unroll
      for (int j = 0; j < 4; ++j) {
        const int off = w4 * 4096 + j * 1024 + l * 16;
        const int row = off >> 7;            // 128 B per mask row
        const int wb  = off & 127;
        gl16(mgb + row * 128 + (wb ^ ((row & 7) << 4)), sMk + off);
      }
    }
  }
  asm volatile("s_waitcnt vmcnt(0)" ::: "memory");

  // ---- x1 B-frags from LDS: 2x ds_read_b128 (f32) + cvt_pk pack ----
  const int xrow = w4 * 32 + q31;
  const uint8_t* xls = sX + xrow * 512;
  const uint xxor = (uint)(xrow & 31) << 4;
  bf16x8 xbf[8];
  #pragma unroll
  for (int kt = 0; kt < 8; ++kt) {
    const uint colb = kt * 64 + hi2 * 32;
    f32x4 a0 = *(const f32x4*)(xls + (colb ^ xxor));
    f32x4 a1 = *(const f32x4*)(xls + ((colb + 16) ^ xxor));
    uintx4 t;
    t.x = pkbf(a0[0], a0[1]); t.y = pkbf(a0[2], a0[3]);
    t.z = pkbf(a1[0], a1[1]); t.w = pkbf(a1[2], a1[3]);
    xbf[kt] = __builtin_bit_cast(bf16x8, t);
  }

  const uint8_t* mls = sMk + xrow * 128;
  const uint mxor = (uint)(xrow & 7) << 4;

  // ---- S^T = M @ x1^T in two j-tile pairs; pack to bf16 pb-frags ----
  const uint* mrowW = (const uint*)x3 + qrow * LK;
  bf16x8 pb[8];

  #pragma unroll
  for (int half = 0; half < 2; ++half) {
    const int jt0 = half * 2, jt1 = half * 2 + 1;
    f32x16 s0 = zero16(), s1 = zero16();
    __builtin_amdgcn_s_setprio(1);
    #pragma unroll
    for (int kt = 0; kt < 8; ++kt) {
      s0 = MFMA32(*(const bf16x8*)(Mf + (((jt0 * 8 + kt) << 10) | (l << 4))),
                  xbf[kt], s0);
      s1 = MFMA32(*(const bf16x8*)(Mf + (((jt1 * 8 + kt) << 10) | (l << 4))),
                  xbf[kt], s1);
    }
    __builtin_amdgcn_s_setprio(0);

    #pragma unroll
    for (int jj = 0; jj < 2; ++jj) {
      f32x16& sj = jj ? s1 : s0;
      const int jt = half * 2 + jj;
      #pragma unroll
      for (int rg = 0; rg < 4; ++rg) {
        uint m0, m1, m2, m3;
        if (byteMode) {
          const uint colm = (uint)(jt * 32 + 8 * rg + 4 * hi2);
          uint u = *(const uint*)(mls + (colm ^ mxor));
          m0 = u & 0xffu; m1 = (u >> 8) & 0xffu; m2 = (u >> 16) & 0xffu; m3 = u >> 24;
        } else {
          uint4 mw = *(const uint4*)(mrowW + jt * 32 + 8 * rg + 4 * hi2);
          m0 = mw.x; m1 = mw.y; m2 = mw.z; m3 = mw.w;
        }
        float p0 = __builtin_amdgcn_exp2f(sj[rg * 4 + 0] * C1);
        float p1 = __builtin_amdgcn_exp2f(sj[rg * 4 + 1] * C1);
        float p2 = __builtin_amdgcn_exp2f(sj[rg * 4 + 2] * C1);
        float p3 = __builtin_amdgcn_exp2f(sj[rg * 4 + 3] * C1);
        sj[rg * 4 + 0] = m0 ? 0.f : p0;
        sj[rg * 4 + 1] = m1 ? 0.f : p1;
        sj[rg * 4 + 2] = m2 ? 0.f : p2;
        sj[rg * 4 + 3] = m3 ? 0.f : p3;
      }

      // P^T B-frags in-register: cvt_pk pairs + permlane32_swap
      #pragma unroll
      for (int h = 0; h < 2; ++h) {
        uint A = pkbf(sj[h * 8 + 0], sj[h * 8 + 1]);
        uint C = pkbf(sj[h * 8 + 2], sj[h * 8 + 3]);
        uint B = pkbf(sj[h * 8 + 4], sj[h * 8 + 5]);
        uint D = pkbf(sj[h * 8 + 6], sj[h * 8 + 7]);
        asm("v_permlane32_swap_b32 %0, %1" : "+v"(A), "+v"(B));
        asm("v_permlane32_swap_b32 %0, %1" : "+v"(C), "+v"(D));
        uintx4 t; t.x = A; t.y = C; t.z = B; t.w = D;
        pb[jt * 2 + h] = __builtin_bit_cast(bf16x8, t);
      }
    }
  }

  // ---- dsum chain + first oc pair (3 independent MFMA chains) ----
  bf16x8 ones1;
  #pragma unroll
  for (int e = 0; e < 8; ++e) ones1[e] = (bf16_t)1.f;

  f32x16 dacc = zero16();
  {
    f32x16 o0 = zero16(), o1 = zero16();
    __builtin_amdgcn_s_setprio(1);
    #pragma unroll
    for (int kt = 0; kt < 8; ++kt) {
      dacc = MFMA32(ones1, pb[kt], dacc);
      o0 = MFMA32(*(const bf16x8*)(Vf + (((0 * 8 + kt) << 10) | (l << 4))), pb[kt], o0);
      o1 = MFMA32(*(const bf16x8*)(Vf + (((1 * 8 + kt) << 10) | (l << 4))), pb[kt], o1);
    }
    __builtin_amdgcn_s_setprio(0);
    const float inv = 1.0f / dacc[0];
    #pragma unroll
    for (int r = 0; r < 16; ++r) {
      const int ibase = (r & 3) + 8 * (r >> 2) + 4 * hi2;
      out[((size_t)b * LK + ibase) * LQ + q0w + q31] = o0[r] * inv;
      out[((size_t)b * LK + 32 + ibase) * LQ + q0w + q31] = o1[r] * inv;
    }
  }

  // ---- second oc pair ----
  {
    f32x16 o2 = zero16(), o3 = zero16();
    __builtin_amdgcn_s_setprio(1);
    #pragma unroll
    for (int kt = 0; kt < 8; ++kt) {
      o2 = MFMA32(*(const bf16x8*)(Vf + (((2 * 8 + kt) << 10) | (l << 4))), pb[kt], o2);
      o3 = MFMA32(*(const bf16x8*)(Vf + (((3 * 8 + kt) << 10) | (l << 4))), pb[kt], o3);
    }
    __builtin_amdgcn_s_setprio(0);
    const float inv = 1.0f / dacc[0];
    #pragma unroll
    for (int r = 0; r < 16; ++r) {
      const int ibase = (r & 3) + 8 * (r >> 2) + 4 * hi2;
      out[((size_t)b * LK + 64 + ibase) * LQ + q0w + q31] = o2[r] * inv;
      out[((size_t)b * LK + 96 + ibase) * LQ + q0w + q31] = o3[r] * inv;
    }
  }
}

extern "C" void kernel_launch(void* const* d_in, const int* in_sizes, int n_in,
                              void* d_out, int out_size, void* d_ws, size_t ws_size,
                              hipStream_t stream) {
  const float* x1 = (const float*)d_in[0];
  const float* x2 = (const float*)d_in[1];
  const void*  x3 = d_in[2];
  const float* wq = (const float*)d_in[3];
  const float* wk = (const float*)d_in[4];
  const float* wv = (const float*)d_in[5];
  uint8_t* ws = (uint8_t*)d_ws;
  float* out = (float*)d_out;

  prep_kernel<<<2 * NB, 512, 0, stream>>>(x2, wq, wk, wv, (const unsigned*)x3, ws);
  attn_kernel<<<NB * (LQ / 128), 256, 0, stream>>>(x1, x3, ws, out);
}

// Round 14
// 47.590 us; speedup vs baseline: 1.2033x; 1.2033x over previous
//
#include <hip/hip_runtime.h>
#include <hip/hip_bf16.h>
#include <stdint.h>

typedef __bf16 bf16_t;
typedef __bf16 bf16x8 __attribute__((ext_vector_type(8)));
typedef float  f32x4  __attribute__((ext_vector_type(4)));
typedef float  f32x16 __attribute__((ext_vector_type(16)));
typedef unsigned int uint;
typedef uint uintx4 __attribute__((ext_vector_type(4)));

#define MFMA16(a,b,c) __builtin_amdgcn_mfma_f32_16x16x32_bf16((a),(b),(c),0,0,0)
#define MFMA32(a,b,c) __builtin_amdgcn_mfma_f32_32x32x16_bf16((a),(b),(c),0,0,0)

constexpr int NB = 16;
constexpr int LQ = 8192;
constexpr int LK = 128;
constexpr int H  = 128;

// log2(e) / sqrt(H): fold softmax scale + exp2 conversion into one multiply
constexpr float C1 = 1.4426950408889634f / 11.313708498984761f;

constexpr size_t WS_FLAG = 0;
constexpr size_t WS_MV   = 1024;   // per batch: [M 32K | V 32K] swizzled bf16 LDS images

// XOR swizzle for [*][128] bf16 LDS tiles (row stride 256 B)
__device__ __forceinline__ unsigned swz(unsigned row, unsigned byte) {
  return row * 256u + (byte ^ ((row & 15u) << 4));
}

__device__ __forceinline__ bf16x8 cvt_frag(const float* p) {
  f32x4 u0 = *(const f32x4*)p;
  f32x4 u1 = *(const f32x4*)(p + 4);
  bf16x8 v;
  #pragma unroll
  for (int e = 0; e < 4; ++e) { v[e] = (bf16_t)u0[e]; v[e + 4] = (bf16_t)u1[e]; }
  return v;
}

__device__ __forceinline__ f32x16 zero16() {
  f32x16 z;
  #pragma unroll
  for (int i = 0; i < 16; ++i) z[i] = 0.f;
  return z;
}

// v_cvt_pk_bf16_f32: lo = bf16(a), hi = bf16(b)
__device__ __forceinline__ uint pkbf(float a, float b) {
  uint d;
  asm("v_cvt_pk_bf16_f32 %0, %1, %2" : "=v"(d) : "v"(a), "v"(b));
  return d;
}

// async global->LDS, 16 bytes per lane
__device__ __forceinline__ void gl16(const void* g, void* l) {
  __builtin_amdgcn_global_load_lds(
      (const __attribute__((address_space(1))) uint32_t*)g,
      (__attribute__((address_space(3))) uint32_t*)l, 16, 0, 0);
}

// ---------------------------------------------------------------------------
// prep (32 blocks): block 2b   -> M_b = x2_b @ (wq^T wk)  (swizzled image to ws)
//                   block 2b+1 -> V_b = x2_b @ wv^T       (swizzled image to ws)
// Block 0 also runs the mask-dtype probe. (unchanged from r8-r10, validated)
// ---------------------------------------------------------------------------
__global__ __launch_bounds__(512) void prep_kernel(
    const float* __restrict__ x2, const float* __restrict__ wq,
    const float* __restrict__ wk, const float* __restrict__ wv,
    const unsigned* __restrict__ x3w, uint8_t* __restrict__ ws)
{
  __shared__ uint8_t sP[131072];  // [wqT 32K | wkT 32K | W2T lin 32K | out 32K]
  __shared__ int sF32, sBig;
  const int tid = threadIdx.x;
  const int b = blockIdx.x >> 1, which = blockIdx.x & 1;
  const int l = tid & 63, w = tid >> 6, q31 = l & 31, hi2 = l >> 5;
  uint8_t* sOut = sP + 98304;

  if (which == 0) {
    if (blockIdx.x == 0) {
      // mask dtype probe over first 2048 words of x3:
      // int32 bool -> words in {0,1}; uint8 bool -> words like 0x01010101 (>1);
      // f32 bool -> words in {0, 0x3f800000}
      if (tid == 0) { sF32 = 0; sBig = 0; }
      __syncthreads();
      int f = 0, g = 0;
      #pragma unroll
      for (int j = 0; j < 4; ++j) {
        unsigned v = x3w[tid * 4 + j];
        if (v == 0x3f800000u) f = 1;
        else if (v > 1u) g = 1;
      }
      if (f) sF32 = 1;
      if (g) sBig = 1;
      __syncthreads();
      if (tid == 0) *(int*)(ws + WS_FLAG) = (sF32 == 0 && sBig == 1) ? 1 : 0;
    }

    // stage wqT / wkT swizzled
    {
      const int row = tid >> 2, c0 = (tid & 3) * 32;
      #pragma unroll
      for (int wh = 0; wh < 2; ++wh) {
        const float* W = wh ? wk : wq;
        uint8_t* dst = sP + wh * 32768;
        const float* s = W + row * H + c0;
        #pragma unroll
        for (int j = 0; j < 32; ++j)
          *(bf16_t*)(dst + swz(c0 + j, row * 2)) = (bf16_t)s[j];
      }
    }
    __syncthreads();

    // W2T[i][j] = sum_k wq[k][i] wk[k][j]  -> LDS linear [128][128] bf16
    {
      const int lo = l & 15, hi = l >> 4;
      bf16x8 a4[4];
      #pragma unroll
      for (int kk = 0; kk < 4; ++kk)
        a4[kk] = *(const bf16x8*)(sP + swz(16 * w + lo, kk * 64 + hi * 16));
      bf16_t* W2T = (bf16_t*)(sP + 65536);
      #pragma unroll
      for (int t = 0; t < 8; ++t) {
        f32x4 c = {0.f, 0.f, 0.f, 0.f};
        #pragma unroll
        for (int kk = 0; kk < 4; ++kk)
          c = MFMA16(a4[kk], *(const bf16x8*)(sP + 32768 + swz(16 * t + lo, kk * 64 + hi * 16)), c);
        #pragma unroll
        for (int r = 0; r < 4; ++r)
          W2T[(16 * w + hi * 4 + r) * H + 16 * t + lo] = (bf16_t)c[r];
      }
    }
    __syncthreads();

    // M build
    if (w < 4) {
      const int wb = w;
      bf16x8 axf[8];
      const float* x2r = x2 + ((size_t)b * LK + 32 * wb + q31) * H;
      #pragma unroll
      for (int kt = 0; kt < 8; ++kt)
        axf[kt] = cvt_frag(x2r + kt * 16 + 8 * hi2);
      const bf16_t* W2Tl = (const bf16_t*)(sP + 65536);
      #pragma unroll
      for (int nt = 0; nt < 4; ++nt) {
        f32x16 c = zero16();
        #pragma unroll
        for (int kt = 0; kt < 8; ++kt)
          c = MFMA32(axf[kt],
                     *(const bf16x8*)(W2Tl + (size_t)(nt * 32 + q31) * H + kt * 16 + 8 * hi2), c);
        #pragma unroll
        for (int r = 0; r < 16; ++r)
          *(bf16_t*)(sOut + swz(32 * wb + (r & 3) + 8 * (r >> 2) + 4 * hi2,
                                (nt * 32 + q31) * 2)) = (bf16_t)c[r];
      }
    }
  } else {
    // V build
    if (w < 4) {
      const int wb = w;
      bf16x8 axf[8];
      const float* x2r = x2 + ((size_t)b * LK + 32 * wb + q31) * H;
      #pragma unroll
      for (int kt = 0; kt < 8; ++kt)
        axf[kt] = cvt_frag(x2r + kt * 16 + 8 * hi2);
      #pragma unroll
      for (int nt = 0; nt < 4; ++nt) {
        f32x16 c = zero16();
        #pragma unroll
        for (int kt = 0; kt < 8; ++kt)
          c = MFMA32(axf[kt],
                     cvt_frag(wv + (size_t)(nt * 32 + q31) * H + kt * 16 + 8 * hi2), c);
        #pragma unroll
        for (int r = 0; r < 16; ++r)
          *(bf16_t*)(sOut + swz(32 * wb + (r & 3) + 8 * (r >> 2) + 4 * hi2,
                                (nt * 32 + q31) * 2)) = (bf16_t)c[r];
      }
    }
  }
  __syncthreads();

  // copy the 32 KB swizzled image to ws (linear)
  {
    const uint4* src = (const uint4*)sOut;
    uint4* dst = (uint4*)(ws + WS_MV + (size_t)b * 65536 + (size_t)which * 32768);
    #pragma unroll
    for (int j = 0; j < 4; ++j)
      dst[tid + j * 512] = src[tid + j * 512];
  }
}

// ---------------------------------------------------------------------------
// Main fused kernel (r10 body) + bijective batch->XCD swizzle.
// All 64 q-chunks of batch b run on XCD b&7 (2 batches per XCD). The XCD's
// 4-MB L2 then holds its own batch's entire 4-MB output region: writes
// accumulate locally with high DRAM page locality instead of 8-XCD-interleaved
// 128-B scatter; the batch's M/V image and x1/mask reads localize too.
// decode: xcd = blk&7; t = blk>>3; b = ((t&1)<<3)|xcd; qchunk = t>>1.
// ---------------------------------------------------------------------------
__global__ __attribute__((amdgpu_flat_work_group_size(512, 512),
                          amdgpu_waves_per_eu(4, 4)))
void attn_kernel(
    const float* __restrict__ x1, const void* __restrict__ x3,
    const uint8_t* __restrict__ ws, float* __restrict__ out)
{
  __shared__ uint8_t sm[65536];
  uint8_t* sM = sm;            // M [128 j][128 c] bf16 swizzled
  uint8_t* sV = sm + 32768;    // V [128 i][128 j] bf16 swizzled

  const int tid = threadIdx.x, blk = blockIdx.x;
  const int xcd = blk & 7;          // hw XCD (round-robin dispatch)
  const int t   = blk >> 3;         // 0..63
  const int b   = ((t & 1) << 3) | xcd;
  const int qc  = (t >> 1) * 256;
  const int l = tid & 63, w = tid >> 6;
  const int q31 = l & 31, hi2 = l >> 5;
  const int byteMode = *(const int*)(ws + WS_FLAG);

  const int q0w = qc + w * 32;
  const size_t qrow = (size_t)b * LQ + q0w + q31;   // this lane's q row

  // ---- M/V image: async global->LDS (64 KB, L2-resident per XCD) ----
  {
    const uint8_t* g = ws + WS_MV + (size_t)b * 65536;
    #pragma unroll
    for (int j = 0; j < 8; ++j)
      gl16(g + tid * 16 + j * 8192, sm + tid * 16 + j * 8192);
  }

  // ---- x1: 16 raw dwordx4 loads per lane ----
  f32x4 xr[16];
  {
    const float* xp = x1 + qrow * H;
    #pragma unroll
    for (int kt = 0; kt < 8; ++kt) {
      xr[2 * kt]     = *(const f32x4*)(xp + kt * 16 + 8 * hi2);
      xr[2 * kt + 1] = *(const f32x4*)(xp + kt * 16 + 8 * hi2 + 4);
    }
  }

  // ---- mask prefetch (byte mode) ----
  uint mu[16];
  if (byteMode) {
    const uint8_t* mp = (const uint8_t*)x3 + qrow * LK;
    #pragma unroll
    for (int jt = 0; jt < 4; ++jt)
      #pragma unroll
      for (int rg = 0; rg < 4; ++rg)
        mu[jt * 4 + rg] = *(const uint*)(mp + jt * 32 + 8 * rg + 4 * hi2);
  }
  __builtin_amdgcn_sched_barrier(0);   // pin: all loads issued before anything else
  __syncthreads();   // drains gload_lds + x1 + mask

  // convert x1 to bf16 B-frags
  bf16x8 xbf[8];
  #pragma unroll
  for (int kt = 0; kt < 8; ++kt)
    #pragma unroll
    for (int e = 0; e < 4; ++e) {
      xbf[kt][e]     = (bf16_t)xr[2 * kt][e];
      xbf[kt][e + 4] = (bf16_t)xr[2 * kt + 1][e];
    }

  // ---- S^T = M @ x1^T in two j-tile pairs; pack to bf16 pb-frags ----
  const uint* mrowW = (const uint*)x3 + qrow * LK;
  bf16x8 pb[8];

  #pragma unroll
  for (int half = 0; half < 2; ++half) {
    const int jt0 = half * 2, jt1 = half * 2 + 1;
    f32x16 s0 = zero16(), s1 = zero16();
    __builtin_amdgcn_s_setprio(1);
    #pragma unroll
    for (int kt = 0; kt < 8; ++kt) {
      s0 = MFMA32(*(const bf16x8*)(sM + swz(jt0 * 32 + q31, kt * 32 + hi2 * 16)),
                  xbf[kt], s0);
      s1 = MFMA32(*(const bf16x8*)(sM + swz(jt1 * 32 + q31, kt * 32 + hi2 * 16)),
                  xbf[kt], s1);
    }
    __builtin_amdgcn_s_setprio(0);

    #pragma unroll
    for (int jj = 0; jj < 2; ++jj) {
      f32x16& sj = jj ? s1 : s0;
      const int jt = half * 2 + jj;
      #pragma unroll
      for (int rg = 0; rg < 4; ++rg) {
        uint m0, m1, m2, m3;
        if (byteMode) {
          uint u = mu[jt * 4 + rg];
          m0 = u & 0xffu; m1 = (u >> 8) & 0xffu; m2 = (u >> 16) & 0xffu; m3 = u >> 24;
        } else {
          uint4 mw = *(const uint4*)(mrowW + jt * 32 + 8 * rg + 4 * hi2);
          m0 = mw.x; m1 = mw.y; m2 = mw.z; m3 = mw.w;
        }
        float p0 = __builtin_amdgcn_exp2f(sj[rg * 4 + 0] * C1);
        float p1 = __builtin_amdgcn_exp2f(sj[rg * 4 + 1] * C1);
        float p2 = __builtin_amdgcn_exp2f(sj[rg * 4 + 2] * C1);
        float p3 = __builtin_amdgcn_exp2f(sj[rg * 4 + 3] * C1);
        sj[rg * 4 + 0] = m0 ? 0.f : p0;
        sj[rg * 4 + 1] = m1 ? 0.f : p1;
        sj[rg * 4 + 2] = m2 ? 0.f : p2;
        sj[rg * 4 + 3] = m3 ? 0.f : p3;
      }

      // P^T B-frags in-register: cvt_pk pairs + permlane32_swap
      #pragma unroll
      for (int h = 0; h < 2; ++h) {
        uint A = pkbf(sj[h * 8 + 0], sj[h * 8 + 1]);
        uint C = pkbf(sj[h * 8 + 2], sj[h * 8 + 3]);
        uint B = pkbf(sj[h * 8 + 4], sj[h * 8 + 5]);
        uint D = pkbf(sj[h * 8 + 6], sj[h * 8 + 7]);
        asm("v_permlane32_swap_b32 %0, %1" : "+v"(A), "+v"(B));
        asm("v_permlane32_swap_b32 %0, %1" : "+v"(C), "+v"(D));
        uintx4 t2; t2.x = A; t2.y = C; t2.z = B; t2.w = D;
        pb[jt * 2 + h] = __builtin_bit_cast(bf16x8, t2);
      }
    }
  }

  // ---- dsum chain + first oc pair (3 independent MFMA chains) ----
  bf16x8 ones1;
  #pragma unroll
  for (int e = 0; e < 8; ++e) ones1[e] = (bf16_t)1.f;

  f32x16 dacc = zero16();
  {
    f32x16 o0 = zero16(), o1 = zero16();
    __builtin_amdgcn_s_setprio(1);
    #pragma unroll
    for (int kt = 0; kt < 8; ++kt) {
      dacc = MFMA32(ones1, pb[kt], dacc);
      o0 = MFMA32(*(const bf16x8*)(sV + swz(0 * 32 + q31, kt * 32 + hi2 * 16)), pb[kt], o0);
      o1 = MFMA32(*(const bf16x8*)(sV + swz(1 * 32 + q31, kt * 32 + hi2 * 16)), pb[kt], o1);
    }
    __builtin_amdgcn_s_setprio(0);
    const float inv = 1.0f / dacc[0];
    #pragma unroll
    for (int r = 0; r < 16; ++r) {
      const int ibase = (r & 3) + 8 * (r >> 2) + 4 * hi2;
      out[((size_t)b * LK + ibase) * LQ + q0w + q31] = o0[r] * inv;
      out[((size_t)b * LK + 32 + ibase) * LQ + q0w + q31] = o1[r] * inv;
    }
  }

  // ---- second oc pair ----
  {
    f32x16 o2 = zero16(), o3 = zero16();
    __builtin_amdgcn_s_setprio(1);
    #pragma unroll
    for (int kt = 0; kt < 8; ++kt) {
      o2 = MFMA32(*(const bf16x8*)(sV + swz(2 * 32 + q31, kt * 32 + hi2 * 16)), pb[kt], o2);
      o3 = MFMA32(*(const bf16x8*)(sV + swz(3 * 32 + q31, kt * 32 + hi2 * 16)), pb[kt], o3);
    }
    __builtin_amdgcn_s_setprio(0);
    const float inv = 1.0f / dacc[0];
    #pragma unroll
    for (int r = 0; r < 16; ++r) {
      const int ibase = (r & 3) + 8 * (r >> 2) + 4 * hi2;
      out[((size_t)b * LK + 64 + ibase) * LQ + q0w + q31] = o2[r] * inv;
      out[((size_t)b * LK + 96 + ibase) * LQ + q0w + q31] = o3[r] * inv;
    }
  }
}

extern "C" void kernel_launch(void* const* d_in, const int* in_sizes, int n_in,
                              void* d_out, int out_size, void* d_ws, size_t ws_size,
                              hipStream_t stream) {
  const float* x1 = (const float*)d_in[0];
  const float* x2 = (const float*)d_in[1];
  const void*  x3 = d_in[2];
  const float* wq = (const float*)d_in[3];
  const float* wk = (const float*)d_in[4];
  const float* wv = (const float*)d_in[5];
  uint8_t* ws = (uint8_t*)d_ws;
  float* out = (float*)d_out;

  prep_kernel<<<2 * NB, 512, 0, stream>>>(x2, wq, wk, wv, (const unsigned*)x3, ws);
  attn_kernel<<<NB * (LQ / 256), 512, 0, stream>>>(x1, x3, ws, out);
}

// Round 15
// 47.397 us; speedup vs baseline: 1.2082x; 1.0041x over previous
//
#include <hip/hip_runtime.h>
#include <hip/hip_bf16.h>
#include <stdint.h>

typedef __bf16 bf16_t;
typedef __bf16 bf16x8 __attribute__((ext_vector_type(8)));
typedef float  f32x4  __attribute__((ext_vector_type(4)));
typedef float  f32x16 __attribute__((ext_vector_type(16)));
typedef unsigned int uint;
typedef uint uintx4 __attribute__((ext_vector_type(4)));

#define MFMA16(a,b,c) __builtin_amdgcn_mfma_f32_16x16x32_bf16((a),(b),(c),0,0,0)
#define MFMA32(a,b,c) __builtin_amdgcn_mfma_f32_32x32x16_bf16((a),(b),(c),0,0,0)

constexpr int NB = 16;
constexpr int LQ = 8192;
constexpr int LK = 128;
constexpr int H  = 128;

// log2(e) / sqrt(H): fold softmax scale + exp2 conversion into one multiply
constexpr float C1 = 1.4426950408889634f / 11.313708498984761f;

constexpr size_t WS_FLAG = 0;
constexpr size_t WS_MV   = 1024;   // per batch: [M 32K | V 32K] swizzled bf16 LDS images

// XOR swizzle for [*][128] bf16 LDS tiles (row stride 256 B)
__device__ __forceinline__ unsigned swz(unsigned row, unsigned byte) {
  return row * 256u + (byte ^ ((row & 15u) << 4));
}

__device__ __forceinline__ bf16x8 cvt_frag(const float* p) {
  f32x4 u0 = *(const f32x4*)p;
  f32x4 u1 = *(const f32x4*)(p + 4);
  bf16x8 v;
  #pragma unroll
  for (int e = 0; e < 4; ++e) { v[e] = (bf16_t)u0[e]; v[e + 4] = (bf16_t)u1[e]; }
  return v;
}

__device__ __forceinline__ f32x16 zero16() {
  f32x16 z;
  #pragma unroll
  for (int i = 0; i < 16; ++i) z[i] = 0.f;
  return z;
}

// v_cvt_pk_bf16_f32: lo = bf16(a), hi = bf16(b)
__device__ __forceinline__ uint pkbf(float a, float b) {
  uint d;
  asm("v_cvt_pk_bf16_f32 %0, %1, %2" : "=v"(d) : "v"(a), "v"(b));
  return d;
}

// async global->LDS, 16 bytes per lane
__device__ __forceinline__ void gl16(const void* g, void* l) {
  __builtin_amdgcn_global_load_lds(
      (const __attribute__((address_space(1))) uint32_t*)g,
      (__attribute__((address_space(3))) uint32_t*)l, 16, 0, 0);
}

// ---------------------------------------------------------------------------
// prep (32 blocks): block 2b   -> M_b = x2_b @ (wq^T wk)  (swizzled image to ws)
//                   block 2b+1 -> V_b = x2_b @ wv^T       (swizzled image to ws)
// Block 0 also runs the mask-dtype probe. (unchanged from r8-r14, validated)
// ---------------------------------------------------------------------------
__global__ __launch_bounds__(512) void prep_kernel(
    const float* __restrict__ x2, const float* __restrict__ wq,
    const float* __restrict__ wk, const float* __restrict__ wv,
    const unsigned* __restrict__ x3w, uint8_t* __restrict__ ws)
{
  __shared__ uint8_t sP[131072];  // [wqT 32K | wkT 32K | W2T lin 32K | out 32K]
  __shared__ int sF32, sBig;
  const int tid = threadIdx.x;
  const int b = blockIdx.x >> 1, which = blockIdx.x & 1;
  const int l = tid & 63, w = tid >> 6, q31 = l & 31, hi2 = l >> 5;
  uint8_t* sOut = sP + 98304;

  if (which == 0) {
    if (blockIdx.x == 0) {
      // mask dtype probe over first 2048 words of x3:
      // int32 bool -> words in {0,1}; uint8 bool -> words like 0x01010101 (>1);
      // f32 bool -> words in {0, 0x3f800000}
      if (tid == 0) { sF32 = 0; sBig = 0; }
      __syncthreads();
      int f = 0, g = 0;
      #pragma unroll
      for (int j = 0; j < 4; ++j) {
        unsigned v = x3w[tid * 4 + j];
        if (v == 0x3f800000u) f = 1;
        else if (v > 1u) g = 1;
      }
      if (f) sF32 = 1;
      if (g) sBig = 1;
      __syncthreads();
      if (tid == 0) *(int*)(ws + WS_FLAG) = (sF32 == 0 && sBig == 1) ? 1 : 0;
    }

    // stage wqT / wkT swizzled
    {
      const int row = tid >> 2, c0 = (tid & 3) * 32;
      #pragma unroll
      for (int wh = 0; wh < 2; ++wh) {
        const float* W = wh ? wk : wq;
        uint8_t* dst = sP + wh * 32768;
        const float* s = W + row * H + c0;
        #pragma unroll
        for (int j = 0; j < 32; ++j)
          *(bf16_t*)(dst + swz(c0 + j, row * 2)) = (bf16_t)s[j];
      }
    }
    __syncthreads();

    // W2T[i][j] = sum_k wq[k][i] wk[k][j]  -> LDS linear [128][128] bf16
    {
      const int lo = l & 15, hi = l >> 4;
      bf16x8 a4[4];
      #pragma unroll
      for (int kk = 0; kk < 4; ++kk)
        a4[kk] = *(const bf16x8*)(sP + swz(16 * w + lo, kk * 64 + hi * 16));
      bf16_t* W2T = (bf16_t*)(sP + 65536);
      #pragma unroll
      for (int t = 0; t < 8; ++t) {
        f32x4 c = {0.f, 0.f, 0.f, 0.f};
        #pragma unroll
        for (int kk = 0; kk < 4; ++kk)
          c = MFMA16(a4[kk], *(const bf16x8*)(sP + 32768 + swz(16 * t + lo, kk * 64 + hi * 16)), c);
        #pragma unroll
        for (int r = 0; r < 4; ++r)
          W2T[(16 * w + hi * 4 + r) * H + 16 * t + lo] = (bf16_t)c[r];
      }
    }
    __syncthreads();

    // M build
    if (w < 4) {
      const int wb = w;
      bf16x8 axf[8];
      const float* x2r = x2 + ((size_t)b * LK + 32 * wb + q31) * H;
      #pragma unroll
      for (int kt = 0; kt < 8; ++kt)
        axf[kt] = cvt_frag(x2r + kt * 16 + 8 * hi2);
      const bf16_t* W2Tl = (const bf16_t*)(sP + 65536);
      #pragma unroll
      for (int nt = 0; nt < 4; ++nt) {
        f32x16 c = zero16();
        #pragma unroll
        for (int kt = 0; kt < 8; ++kt)
          c = MFMA32(axf[kt],
                     *(const bf16x8*)(W2Tl + (size_t)(nt * 32 + q31) * H + kt * 16 + 8 * hi2), c);
        #pragma unroll
        for (int r = 0; r < 16; ++r)
          *(bf16_t*)(sOut + swz(32 * wb + (r & 3) + 8 * (r >> 2) + 4 * hi2,
                                (nt * 32 + q31) * 2)) = (bf16_t)c[r];
      }
    }
  } else {
    // V build
    if (w < 4) {
      const int wb = w;
      bf16x8 axf[8];
      const float* x2r = x2 + ((size_t)b * LK + 32 * wb + q31) * H;
      #pragma unroll
      for (int kt = 0; kt < 8; ++kt)
        axf[kt] = cvt_frag(x2r + kt * 16 + 8 * hi2);
      #pragma unroll
      for (int nt = 0; nt < 4; ++nt) {
        f32x16 c = zero16();
        #pragma unroll
        for (int kt = 0; kt < 8; ++kt)
          c = MFMA32(axf[kt],
                     cvt_frag(wv + (size_t)(nt * 32 + q31) * H + kt * 16 + 8 * hi2), c);
        #pragma unroll
        for (int r = 0; r < 16; ++r)
          *(bf16_t*)(sOut + swz(32 * wb + (r & 3) + 8 * (r >> 2) + 4 * hi2,
                                (nt * 32 + q31) * 2)) = (bf16_t)c[r];
      }
    }
  }
  __syncthreads();

  // copy the 32 KB swizzled image to ws (linear)
  {
    const uint4* src = (const uint4*)sOut;
    uint4* dst = (uint4*)(ws + WS_MV + (size_t)b * 65536 + (size_t)which * 32768);
    #pragma unroll
    for (int j = 0; j < 4; ++j)
      dst[tid + j * 512] = src[tid + j * 512];
  }
}

// ---- pass macros (straight-line, register-resident; rule #20: no dyn idx) ----

// S + softmax + pb from raw xr/mask regs
#define CONV_S_PB(XR, MU, QROW)                                                \
  {                                                                            \
    bf16x8 xbf[8];                                                             \
    _Pragma("unroll")                                                          \
    for (int kt = 0; kt < 8; ++kt) {                                           \
      _Pragma("unroll")                                                        \
      for (int e = 0; e < 4; ++e) {                                            \
        xbf[kt][e]     = (bf16_t)XR[2 * kt][e];                                \
        xbf[kt][e + 4] = (bf16_t)XR[2 * kt + 1][e];                            \
      }                                                                        \
    }                                                                          \
    const uint* mrowW = (const uint*)x3 + (QROW) * LK;                         \
    _Pragma("unroll")                                                          \
    for (int half = 0; half < 2; ++half) {                                     \
      const int jt0 = half * 2, jt1 = half * 2 + 1;                            \
      f32x16 s0 = zero16(), s1 = zero16();                                     \
      __builtin_amdgcn_s_setprio(1);                                           \
      _Pragma("unroll")                                                        \
      for (int kt = 0; kt < 8; ++kt) {                                         \
        s0 = MFMA32(*(const bf16x8*)(sM + swz(jt0 * 32 + q31, kt * 32 + hi2 * 16)), \
                    xbf[kt], s0);                                              \
        s1 = MFMA32(*(const bf16x8*)(sM + swz(jt1 * 32 + q31, kt * 32 + hi2 * 16)), \
                    xbf[kt], s1);                                              \
      }                                                                        \
      __builtin_amdgcn_s_setprio(0);                                           \
      _Pragma("unroll")                                                        \
      for (int jj = 0; jj < 2; ++jj) {                                         \
        f32x16& sj = jj ? s1 : s0;                                             \
        const int jt = half * 2 + jj;                                          \
        _Pragma("unroll")                                                      \
        for (int rg = 0; rg < 4; ++rg) {                                       \
          uint m0, m1, m2, m3;                                                 \
          if (byteMode) {                                                      \
            uint u = MU[jt * 4 + rg];                                          \
            m0 = u & 0xffu; m1 = (u >> 8) & 0xffu;                             \
            m2 = (u >> 16) & 0xffu; m3 = u >> 24;                              \
          } else {                                                             \
            uint4 mw = *(const uint4*)(mrowW + jt * 32 + 8 * rg + 4 * hi2);    \
            m0 = mw.x; m1 = mw.y; m2 = mw.z; m3 = mw.w;                        \
          }                                                                    \
          float p0 = __builtin_amdgcn_exp2f(sj[rg * 4 + 0] * C1);              \
          float p1 = __builtin_amdgcn_exp2f(sj[rg * 4 + 1] * C1);              \
          float p2 = __builtin_amdgcn_exp2f(sj[rg * 4 + 2] * C1);              \
          float p3 = __builtin_amdgcn_exp2f(sj[rg * 4 + 3] * C1);              \
          sj[rg * 4 + 0] = m0 ? 0.f : p0;                                      \
          sj[rg * 4 + 1] = m1 ? 0.f : p1;                                      \
          sj[rg * 4 + 2] = m2 ? 0.f : p2;                                      \
          sj[rg * 4 + 3] = m3 ? 0.f : p3;                                      \
        }                                                                      \
        _Pragma("unroll")                                                      \
        for (int h = 0; h < 2; ++h) {                                          \
          uint A = pkbf(sj[h * 8 + 0], sj[h * 8 + 1]);                         \
          uint C = pkbf(sj[h * 8 + 2], sj[h * 8 + 3]);                         \
          uint B = pkbf(sj[h * 8 + 4], sj[h * 8 + 5]);                         \
          uint D = pkbf(sj[h * 8 + 6], sj[h * 8 + 7]);                         \
          asm("v_permlane32_swap_b32 %0, %1" : "+v"(A), "+v"(B));              \
          asm("v_permlane32_swap_b32 %0, %1" : "+v"(C), "+v"(D));              \
          uintx4 t2; t2.x = A; t2.y = C; t2.z = B; t2.w = D;                   \
          pb[jt * 2 + h] = __builtin_bit_cast(bf16x8, t2);                     \
        }                                                                      \
      }                                                                        \
    }                                                                          \
  }

// dsum + O tiles + non-temporal stores for pass at q column Q0W
#define O_STORE(Q0W)                                                           \
  {                                                                            \
    f32x16 dacc = zero16();                                                    \
    {                                                                          \
      f32x16 o0 = zero16(), o1 = zero16();                                     \
      __builtin_amdgcn_s_setprio(1);                                           \
      _Pragma("unroll")                                                        \
      for (int kt = 0; kt < 8; ++kt) {                                         \
        dacc = MFMA32(ones1, pb[kt], dacc);                                    \
        o0 = MFMA32(*(const bf16x8*)(sV + swz(0 * 32 + q31, kt * 32 + hi2 * 16)), pb[kt], o0); \
        o1 = MFMA32(*(const bf16x8*)(sV + swz(1 * 32 + q31, kt * 32 + hi2 * 16)), pb[kt], o1); \
      }                                                                        \
      __builtin_amdgcn_s_setprio(0);                                           \
      const float inv = 1.0f / dacc[0];                                        \
      _Pragma("unroll")                                                        \
      for (int r = 0; r < 16; ++r) {                                           \
        const int ibase = (r & 3) + 8 * (r >> 2) + 4 * hi2;                    \
        __builtin_nontemporal_store(o0[r] * inv,                               \
            &out[((size_t)b * LK + ibase) * LQ + (Q0W) + q31]);                \
        __builtin_nontemporal_store(o1[r] * inv,                               \
            &out[((size_t)b * LK + 32 + ibase) * LQ + (Q0W) + q31]);           \
      }                                                                        \
      f32x16 o2 = zero16(), o3 = zero16();                                     \
      __builtin_amdgcn_s_setprio(1);                                           \
      _Pragma("unroll")                                                        \
      for (int kt = 0; kt < 8; ++kt) {                                         \
        o2 = MFMA32(*(const bf16x8*)(sV + swz(2 * 32 + q31, kt * 32 + hi2 * 16)), pb[kt], o2); \
        o3 = MFMA32(*(const bf16x8*)(sV + swz(3 * 32 + q31, kt * 32 + hi2 * 16)), pb[kt], o3); \
      }                                                                        \
      __builtin_amdgcn_s_setprio(0);                                           \
      _Pragma("unroll")                                                        \
      for (int r = 0; r < 16; ++r) {                                           \
        const int ibase = (r & 3) + 8 * (r >> 2) + 4 * hi2;                    \
        __builtin_nontemporal_store(o2[r] * inv,                               \
            &out[((size_t)b * LK + 64 + ibase) * LQ + (Q0W) + q31]);           \
        __builtin_nontemporal_store(o3[r] * inv,                               \
            &out[((size_t)b * LK + 96 + ibase) * LQ + (Q0W) + q31]);           \
      }                                                                        \
    }                                                                          \
  }

// ---------------------------------------------------------------------------
// Main fused kernel — r14 math, two pipelined subtile passes per wave +
// non-temporal output stores.
// Block = 256 threads (4 waves x 2 subtiles of 32 rows = 256 rows); grid 512
// with r14's bijective batch->XCD swizzle. Pass-1's x1/mask loads issue
// between pass-0's softmax and pass-0's O/store phase, so pass-0 writes
// overlap pass-1 reads (mixed HBM traffic instead of serialized phases).
// __launch_bounds__(256,2): 256-VGPR budget keeps xr1[16] live across the
// store phase. NT stores bypass L2 -> the M/V image + read streams stay hot.
// LDS 64 KB -> 2 blocks/CU = 8 waves/CU.
// ---------------------------------------------------------------------------
__global__ __launch_bounds__(256, 2) void attn_kernel(
    const float* __restrict__ x1, const void* __restrict__ x3,
    const uint8_t* __restrict__ ws, float* __restrict__ out)
{
  __shared__ uint8_t sm[65536];
  uint8_t* sM = sm;            // M [128 j][128 c] bf16 swizzled
  uint8_t* sV = sm + 32768;    // V [128 i][128 j] bf16 swizzled

  const int tid = threadIdx.x, blk = blockIdx.x;
  const int xcd = blk & 7;          // hw XCD (round-robin dispatch)
  const int t   = blk >> 3;         // 0..63
  const int b   = ((t & 1) << 3) | xcd;
  const int qc  = (t >> 1) * 256;
  const int l = tid & 63, w4 = tid >> 6;
  const int q31 = l & 31, hi2 = l >> 5;
  const int byteMode = *(const int*)(ws + WS_FLAG);

  const int q0w0 = qc + w4 * 64;        // pass-0 columns
  const int q0w1 = q0w0 + 32;           // pass-1 columns
  const size_t qrow0 = (size_t)b * LQ + q0w0 + q31;
  const size_t qrow1 = qrow0 + 32;

  // ---- M/V image: async global->LDS (64 KB; 16 gl16 per thread) ----
  {
    const uint8_t* g = ws + WS_MV + (size_t)b * 65536;
    #pragma unroll
    for (int j = 0; j < 16; ++j)
      gl16(g + tid * 16 + j * 4096, sm + tid * 16 + j * 4096);
  }

  // ---- pass-0 x1 + mask loads ----
  f32x4 xr0[16];
  uint mu0[16];
  {
    const float* xp = x1 + qrow0 * H;
    #pragma unroll
    for (int kt = 0; kt < 8; ++kt) {
      xr0[2 * kt]     = *(const f32x4*)(xp + kt * 16 + 8 * hi2);
      xr0[2 * kt + 1] = *(const f32x4*)(xp + kt * 16 + 8 * hi2 + 4);
    }
    if (byteMode) {
      const uint8_t* mp = (const uint8_t*)x3 + qrow0 * LK;
      #pragma unroll
      for (int jt = 0; jt < 4; ++jt)
        #pragma unroll
        for (int rg = 0; rg < 4; ++rg)
          mu0[jt * 4 + rg] = *(const uint*)(mp + jt * 32 + 8 * rg + 4 * hi2);
    }
  }
  __syncthreads();   // drains gl16 image + pass-0 loads

  bf16x8 ones1;
  #pragma unroll
  for (int e = 0; e < 8; ++e) ones1[e] = (bf16_t)1.f;

  bf16x8 pb[8];

  // ---- pass 0: S + softmax + pb ----
  CONV_S_PB(xr0, mu0, qrow0)

  // ---- issue pass-1 loads (overlap with pass-0 O/store phase) ----
  f32x4 xr1[16];
  uint mu1[16];
  {
    const float* xp = x1 + qrow1 * H;
    #pragma unroll
    for (int kt = 0; kt < 8; ++kt) {
      xr1[2 * kt]     = *(const f32x4*)(xp + kt * 16 + 8 * hi2);
      xr1[2 * kt + 1] = *(const f32x4*)(xp + kt * 16 + 8 * hi2 + 4);
    }
    if (byteMode) {
      const uint8_t* mp = (const uint8_t*)x3 + qrow1 * LK;
      #pragma unroll
      for (int jt = 0; jt < 4; ++jt)
        #pragma unroll
        for (int rg = 0; rg < 4; ++rg)
          mu1[jt * 4 + rg] = *(const uint*)(mp + jt * 32 + 8 * rg + 4 * hi2);
    }
  }

  // ---- pass 0: O + NT stores (pass-1 loads in flight) ----
  O_STORE(q0w0)

  // ---- pass 1 ----
  CONV_S_PB(xr1, mu1, qrow1)
  O_STORE(q0w1)
}

extern "C" void kernel_launch(void* const* d_in, const int* in_sizes, int n_in,
                              void* d_out, int out_size, void* d_ws, size_t ws_size,
                              hipStream_t stream) {
  const float* x1 = (const float*)d_in[0];
  const float* x2 = (const float*)d_in[1];
  const void*  x3 = d_in[2];
  const float* wq = (const float*)d_in[3];
  const float* wk = (const float*)d_in[4];
  const float* wv = (const float*)d_in[5];
  uint8_t* ws = (uint8_t*)d_ws;
  float* out = (float*)d_out;

  prep_kernel<<<2 * NB, 512, 0, stream>>>(x2, wq, wk, wv, (const unsigned*)x3, ws);
  attn_kernel<<<NB * (LQ / 256), 256, 0, stream>>>(x1, x3, ws, out);
}